// Round 9
// baseline (78.129 us; speedup 1.0000x reference)
//
#include <hip/hip_runtime.h>
#include <hip/hip_bf16.h>

#define B_SZ 4096
#define N_SZ 8192
#define D_SZ 128
#define NRB 64        // number of 128-row/col blocks (N/128)
#define NTRI 2080     // NRB*(NRB+1)/2 upper-triangle blocks
#define XCHUNK 260    // NTRI / 8 XCDs (exact)

constexpr float TEMP = 0.5f;
constexpr float EPS = 1e-8f;
// exp(dot/TEMP) = exp2(dot * log2(e)/TEMP); sqrt of the scale folded into
// BOTH normalized vectors so the MFMA accumulator is directly the exp2 arg.
constexpr float SQS = 1.6986436006556212f;  // sqrt(log2(e)/TEMP)

typedef short short8 __attribute__((ext_vector_type(8)));
typedef float f32x16 __attribute__((ext_vector_type(16)));

// Tiled pn layout (bf16): byte addr of element (row r, col d) =
//   (r>>5)*8192 + (d>>3)*512 + (r&31)*16 + (d&7)*2
// -> each MFMA fragment chunk is 512B contiguous across 32 lanes; a whole
//    32-row tile is one contiguous 8KB block.

// ---------------------------------------------------------------------------
// Kernel A: per wave, handle row pair (r, r+B). Normalize into tiled-bf16 pn
// (scaled by SQS); exact-f32 positive-pair term -> posbuf[block];
// selfexp[r] = exp2(self-sim of the ROUNDED bf16 row) for later diag removal.
// Block 0 thread 0 also zeroes the output accumulator.
// ---------------------------------------------------------------------------
__global__ void norm_pos_kernel(const float* __restrict__ z_i,
                                const float* __restrict__ z_j,
                                unsigned int* __restrict__ pn_u32,
                                float* __restrict__ posbuf,
                                float* __restrict__ selfexp,
                                float* __restrict__ out) {
    __shared__ float sp[4];
    int wid = threadIdx.x >> 6;
    int lane = threadIdx.x & 63;
    int r = blockIdx.x * 4 + wid;                 // [0, B)
    if (blockIdx.x == 0 && threadIdx.x == 0) out[0] = 0.0f;
    float2 vi = *reinterpret_cast<const float2*>(z_i + (size_t)r * D_SZ + lane * 2);
    float2 vj = *reinterpret_cast<const float2*>(z_j + (size_t)r * D_SZ + lane * 2);
    float ssi = vi.x * vi.x + vi.y * vi.y;
    float ssj = vj.x * vj.x + vj.y * vj.y;
    float dot = vi.x * vj.x + vi.y * vj.y;
#pragma unroll
    for (int m = 32; m >= 1; m >>= 1) {
        ssi += __shfl_xor(ssi, m, 64);
        ssj += __shfl_xor(ssj, m, 64);
        dot += __shfl_xor(dot, m, 64);
    }
    float ni = fmaxf(sqrtf(ssi), EPS);
    float nj = fmaxf(sqrtf(ssj), EPS);
    float si = SQS / ni, sj = SQS / nj;
    union { unsigned int u32; __hip_bfloat16 h[2]; } pki, pkj;
    pki.h[0] = __float2bfloat16(vi.x * si);
    pki.h[1] = __float2bfloat16(vi.y * si);
    pkj.h[0] = __float2bfloat16(vj.x * sj);
    pkj.h[1] = __float2bfloat16(vj.y * sj);
    // tiled store: lane l holds cols 2l, 2l+1 (one u32)
    int u = ((r >> 5) * 2048) + ((lane >> 2) * 128) + ((r & 31) * 4) + (lane & 3);
    pn_u32[u] = pki.u32;
    int r2 = r + B_SZ;
    int u2 = ((r2 >> 5) * 2048) + ((lane >> 2) * 128) + ((r2 & 31) * 4) + (lane & 3);
    pn_u32[u2] = pkj.u32;
    // self-similarity of the rounded rows (exp2 units, same scale as MFMA)
    float bx = __bfloat162float(pki.h[0]), by = __bfloat162float(pki.h[1]);
    float cx = __bfloat162float(pkj.h[0]), cy = __bfloat162float(pkj.h[1]);
    float sdi = bx * bx + by * by;
    float sdj = cx * cx + cy * cy;
#pragma unroll
    for (int m = 32; m >= 1; m >>= 1) {
        sdi += __shfl_xor(sdi, m, 64);
        sdj += __shfl_xor(sdj, m, 64);
    }
    if (lane == 0) {
        selfexp[r] = __builtin_amdgcn_exp2f(sdi);
        selfexp[r2] = __builtin_amdgcn_exp2f(sdj);
        sp[wid] = -dot / (ni * nj * TEMP) / (float)B_SZ;
    }
    __syncthreads();
    if (threadIdx.x == 0)
        posbuf[blockIdx.x] = sp[0] + sp[1] + sp[2] + sp[3];
}

// ---------------------------------------------------------------------------
// Kernel B (SYMMETRIC): upper-triangle 128x128 tile blocks over the 64x64
// block grid. Block (i,j), i<=j: rows R=[128i,+128), cols C=[128j,+128).
//   i==j: full square, rowsum only (self-sim removed later via selfexp).
//   i< j: rowsum for R  AND  colsum (mirror, = rowsum for rows in C).
// Slots (no atomics, no zeroing needed):
//   partial[j     ][r in R] — rowsum contribution of block (i,j)
//   partial[64 + i][c in C] — colsum contribution of block (i,j), i<j
// For row r (bi=r>>7) exactly slots {j>=bi} u {64+i : i<bi} are written = 64.
// 2 waves x 2 row-tiles; 4 col-tiles double-buffered via global_load_lds.
// XCD-bijective swizzle (2080 = 8*260), column-major triangle decode keeps
// each XCD in a contiguous j-band (B-strip L2 locality).
// C/D layout: col=lane&31, row=(reg&3)+8*(reg>>2)+4*(lane>>5).
// ---------------------------------------------------------------------------
__global__ __launch_bounds__(128, 4)
void simexp_kernel(const char* __restrict__ p, float* __restrict__ partial) {
    __shared__ char bufA[8192];
    __shared__ char bufB[8192];
    __shared__ float colred[2][128];
    int wid = threadIdx.x >> 6;
    int lane = threadIdx.x & 63;
    int half = lane >> 5, lc = lane & 31;

    int swz = (blockIdx.x & 7) * XCHUNK + (blockIdx.x >> 3);
    // column-major upper-triangle decode: swz = j*(j+1)/2 + i, i <= j
    int j = (int)((sqrtf(8.0f * (float)swz + 1.0f) - 1.0f) * 0.5f);
    while ((j + 1) * (j + 2) / 2 <= swz) ++j;
    while (j * (j + 1) / 2 > swz) --j;
    int i = swz - j * (j + 1) / 2;
    bool doCol = (i < j);

    int rt0 = i * 4 + wid * 2;     // row-tiles (32-row units): rt0, rt0+1
    int ct0 = j * 4;               // first col-tile of strip j

    // A fragments: coalesced 1KB loads, held for the whole kernel
    const char* afrag = p + (size_t)rt0 * 8192 + half * 512 + lc * 16;
    short8 a0[8], a1[8];
#pragma unroll
    for (int kc = 0; kc < 8; ++kc) {
        a0[kc] = *reinterpret_cast<const short8*>(afrag + kc * 1024);
        a1[kc] = *reinterpret_cast<const short8*>(afrag + 8192 + kc * 1024);
    }

    float rs0[16], rs1[16];
#pragma unroll
    for (int q = 0; q < 16; ++q) { rs0[q] = 0.0f; rs1[q] = 0.0f; }
    float cs0 = 0.0f, cs1 = 0.0f, cs2 = 0.0f, cs3 = 0.0f;

    // each wave stages 4 of the 8 1KB segments of one 8KB col-tile
    auto stageHalf = [&](char* buf, int ct) {
#pragma unroll
        for (int sg = 0; sg < 4; ++sg) {
            int seg = wid * 4 + sg;
            const char* g = p + (size_t)ct * 8192 + seg * 1024 + lane * 16;
            __builtin_amdgcn_global_load_lds(
                (const __attribute__((address_space(1))) unsigned int*)g,
                (__attribute__((address_space(3))) unsigned int*)(buf + seg * 1024),
                16, 0, 0);
        }
    };

    auto compute = [&](const char* buf, float& cs) {
        const char* bb = buf + half * 512 + lc * 16;
        short8 b[8];
#pragma unroll
        for (int kc = 0; kc < 8; ++kc)
            b[kc] = *reinterpret_cast<const short8*>(bb + kc * 1024);
        f32x16 acc0 = {}, acc1 = {};
#pragma unroll
        for (int kc = 0; kc < 8; ++kc) {
            acc0 = __builtin_amdgcn_mfma_f32_32x32x16_bf16(a0[kc], b[kc], acc0, 0, 0, 0);
            acc1 = __builtin_amdgcn_mfma_f32_32x32x16_bf16(a1[kc], b[kc], acc1, 0, 0, 0);
        }
        float c01 = 0.0f;
#pragma unroll
        for (int q = 0; q < 16; ++q) {
            float e0 = __builtin_amdgcn_exp2f(acc0[q]);
            float e1 = __builtin_amdgcn_exp2f(acc1[q]);
            rs0[q] += e0;
            rs1[q] += e1;
            c01 += e0 + e1;
        }
        if (doCol) {                      // block-uniform branch
            c01 += __shfl_xor(c01, 32, 64);
            cs = c01;                     // full 64-row colsum, col = ct*32+lc
        }
    };

    stageHalf(bufA, ct0 + 0);
    __syncthreads();
    stageHalf(bufB, ct0 + 1);
    compute(bufA, cs0);
    __syncthreads();
    stageHalf(bufA, ct0 + 2);
    compute(bufB, cs1);
    __syncthreads();
    stageHalf(bufB, ct0 + 3);
    compute(bufA, cs2);
    __syncthreads();
    compute(bufB, cs3);

    // rowsum: reduce across the 32 column lanes
#pragma unroll
    for (int m = 1; m <= 16; m <<= 1) {
#pragma unroll
        for (int q = 0; q < 16; ++q) {
            rs0[q] += __shfl_xor(rs0[q], m, 64);
            rs1[q] += __shfl_xor(rs1[q], m, 64);
        }
    }
    if (lc == 0) {
        float* dst = partial + (size_t)j * N_SZ;
#pragma unroll
        for (int q = 0; q < 16; ++q) {
            int lrow = (q & 3) + 8 * (q >> 2) + 4 * half;
            dst[rt0 * 32 + lrow] = rs0[q];
            dst[(rt0 + 1) * 32 + lrow] = rs1[q];
        }
    }

    // colsum: combine the 2 waves via LDS, store to slot 64+i
    if (doCol) {
        if (half == 0) {
            colred[wid][0 * 32 + lc] = cs0;
            colred[wid][1 * 32 + lc] = cs1;
            colred[wid][2 * 32 + lc] = cs2;
            colred[wid][3 * 32 + lc] = cs3;
        }
        __syncthreads();
        int c = threadIdx.x;  // [0,128)
        partial[(size_t)(NRB + i) * N_SZ + j * 128 + c] =
            colred[0][c] + colred[1][c];
    }
}

// ---------------------------------------------------------------------------
// Kernel C: loss = sum(log(rowsum - selfexp))/2B + pos partials.
// 128 blocks x 64 threads. Row r reads its exactly-written 64 slots:
// rowpart slots j in [bi,64), colpart slots 64+i for i in [0,bi), bi=r>>7.
// ---------------------------------------------------------------------------
__global__ void lse_kernel(const float* __restrict__ partial,
                           const float* __restrict__ selfexp,
                           const float* __restrict__ posbuf,
                           float* __restrict__ out) {
    int r = blockIdx.x * 64 + threadIdx.x;
    int bi = r >> 7;   // uniform within a block (64 consecutive rows)
    float s = 0.0f;
    for (int jj = bi; jj < NRB; ++jj) s += partial[(size_t)jj * N_SZ + r];
    for (int ii = 0; ii < bi; ++ii) s += partial[(size_t)(NRB + ii) * N_SZ + r];
    s -= selfexp[r];
    float v = __logf(s) * (1.0f / (float)N_SZ);
    if (threadIdx.x < 8) v += posbuf[blockIdx.x * 8 + threadIdx.x];
#pragma unroll
    for (int m = 32; m >= 1; m >>= 1) v += __shfl_xor(v, m, 64);
    if (threadIdx.x == 0)
        atomicAdd(out, v);
}

// ---------------------------------------------------------------------------
extern "C" void kernel_launch(void* const* d_in, const int* in_sizes, int n_in,
                              void* d_out, int out_size, void* d_ws, size_t ws_size,
                              hipStream_t stream) {
    const float* z_i = (const float*)d_in[0];
    const float* z_j = (const float*)d_in[1];
    float* out = (float*)d_out;
    char* ws = (char*)d_ws;

    unsigned int* pn = (unsigned int*)ws;                            // 2 MiB
    float* partial = (float*)(ws + (size_t)N_SZ * D_SZ * 2);         // 4 MiB (128 x 8192)
    float* selfexp = partial + (size_t)2 * NRB * N_SZ;               // 32 KiB
    float* posbuf = selfexp + N_SZ;                                  // 4 KiB

    norm_pos_kernel<<<B_SZ / 4, 256, 0, stream>>>(z_i, z_j, pn, posbuf,
                                                  selfexp, out);

    simexp_kernel<<<NTRI, 128, 0, stream>>>((const char*)pn, partial);

    lse_kernel<<<N_SZ / 64, 64, 0, stream>>>(partial, selfexp, posbuf, out);
}

// Round 10
// 50.489 us; speedup vs baseline: 1.5475x; 1.5475x over previous
//
#include <hip/hip_runtime.h>
#include <hip/hip_bf16.h>

#define B_SZ 4096
#define N_SZ 8192
#define D_SZ 128
#define NRB 64        // number of 128-row/col blocks (N/128)
#define NTRI 2080     // NRB*(NRB+1)/2 upper-triangle blocks
#define XCHUNK 260    // NTRI / 8 XCDs (exact)

constexpr float TEMP = 0.5f;
constexpr float EPS = 1e-8f;
// exp(dot/TEMP) = exp2(dot * log2(e)/TEMP); sqrt of the scale folded into
// BOTH normalized vectors so the MFMA accumulator is directly the exp2 arg.
constexpr float SQS = 1.6986436006556212f;  // sqrt(log2(e)/TEMP)

typedef short short8 __attribute__((ext_vector_type(8)));
typedef float f32x16 __attribute__((ext_vector_type(16)));

// Tiled pn layout (bf16): byte addr of element (row r, col d) =
//   (r>>5)*8192 + (d>>3)*512 + (r&31)*16 + (d&7)*2
// -> each MFMA fragment chunk is 512B contiguous across 32 lanes; a whole
//    32-row tile is one contiguous 8KB block.

// ---------------------------------------------------------------------------
// Kernel A: per wave, handle row pair (r, r+B). Normalize into tiled-bf16 pn
// (scaled by SQS); exact-f32 positive-pair term -> posbuf[block];
// selfexp[r] = exp2(self-sim of the ROUNDED bf16 row) for later diag removal.
// Block 0 thread 0 also zeroes the output accumulator.
// ---------------------------------------------------------------------------
__global__ void norm_pos_kernel(const float* __restrict__ z_i,
                                const float* __restrict__ z_j,
                                unsigned int* __restrict__ pn_u32,
                                float* __restrict__ posbuf,
                                float* __restrict__ selfexp,
                                float* __restrict__ out) {
    __shared__ float sp[4];
    int wid = threadIdx.x >> 6;
    int lane = threadIdx.x & 63;
    int r = blockIdx.x * 4 + wid;                 // [0, B)
    if (blockIdx.x == 0 && threadIdx.x == 0) out[0] = 0.0f;
    float2 vi = *reinterpret_cast<const float2*>(z_i + (size_t)r * D_SZ + lane * 2);
    float2 vj = *reinterpret_cast<const float2*>(z_j + (size_t)r * D_SZ + lane * 2);
    float ssi = vi.x * vi.x + vi.y * vi.y;
    float ssj = vj.x * vj.x + vj.y * vj.y;
    float dot = vi.x * vj.x + vi.y * vj.y;
#pragma unroll
    for (int m = 32; m >= 1; m >>= 1) {
        ssi += __shfl_xor(ssi, m, 64);
        ssj += __shfl_xor(ssj, m, 64);
        dot += __shfl_xor(dot, m, 64);
    }
    float ni = fmaxf(sqrtf(ssi), EPS);
    float nj = fmaxf(sqrtf(ssj), EPS);
    float si = SQS / ni, sj = SQS / nj;
    union { unsigned int u32; __hip_bfloat16 h[2]; } pki, pkj;
    pki.h[0] = __float2bfloat16(vi.x * si);
    pki.h[1] = __float2bfloat16(vi.y * si);
    pkj.h[0] = __float2bfloat16(vj.x * sj);
    pkj.h[1] = __float2bfloat16(vj.y * sj);
    // tiled store: lane l holds cols 2l, 2l+1 (one u32)
    int u = ((r >> 5) * 2048) + ((lane >> 2) * 128) + ((r & 31) * 4) + (lane & 3);
    pn_u32[u] = pki.u32;
    int r2 = r + B_SZ;
    int u2 = ((r2 >> 5) * 2048) + ((lane >> 2) * 128) + ((r2 & 31) * 4) + (lane & 3);
    pn_u32[u2] = pkj.u32;
    // self-similarity of the rounded rows (exp2 units, same scale as MFMA)
    float bx = __bfloat162float(pki.h[0]), by = __bfloat162float(pki.h[1]);
    float cx = __bfloat162float(pkj.h[0]), cy = __bfloat162float(pkj.h[1]);
    float sdi = bx * bx + by * by;
    float sdj = cx * cx + cy * cy;
#pragma unroll
    for (int m = 32; m >= 1; m >>= 1) {
        sdi += __shfl_xor(sdi, m, 64);
        sdj += __shfl_xor(sdj, m, 64);
    }
    if (lane == 0) {
        selfexp[r] = __builtin_amdgcn_exp2f(sdi);
        selfexp[r2] = __builtin_amdgcn_exp2f(sdj);
        sp[wid] = -dot / (ni * nj * TEMP) / (float)B_SZ;
    }
    __syncthreads();
    if (threadIdx.x == 0)
        posbuf[blockIdx.x] = sp[0] + sp[1] + sp[2] + sp[3];
}

// ---------------------------------------------------------------------------
// Kernel B (SYMMETRIC): upper-triangle 128x128 tile blocks over the 64x64
// block grid. Block (i,j), i<=j: rows R=[128i,+128), cols C=[128j,+128).
//   i==j: full square, rowsum only (self-sim removed later via selfexp).
//   i< j: rowsum for R  AND  colsum (mirror, = rowsum for rows in C).
// Slots (no atomics, no zeroing needed):
//   partial[j     ][r in R] — rowsum contribution of block (i,j)
//   partial[64 + i][c in C] — colsum contribution of block (i,j), i<j
// For row r (bi=r>>7) exactly slots {j>=bi} u {64+i : i<bi} are written = 64.
// 2 waves x 2 row-tiles; 4 col-tiles double-buffered via global_load_lds.
// XCD-bijective swizzle (2080 = 8*260), column-major triangle decode keeps
// each XCD in a contiguous j-band (B-strip L2 locality).
// __launch_bounds__(128, 2): unified VGPR+AGPR cap 256/wave — kernel needs
// ~100 arch + 32 acc = 132. (128,4) capped it at 128 -> 90 regs/thread
// SPILLED to scratch (r9: FETCH 58MB, WRITE 92MB, 2x regression). Hardware
// still co-schedules ~4 waves/SIMD from the pool; the bound must not choke
// the allocator.
// C/D layout: col=lane&31, row=(reg&3)+8*(reg>>2)+4*(lane>>5).
// ---------------------------------------------------------------------------
__global__ __launch_bounds__(128, 2)
void simexp_kernel(const char* __restrict__ p, float* __restrict__ partial) {
    __shared__ char bufA[8192];
    __shared__ char bufB[8192];
    __shared__ float colred[2][128];
    int wid = threadIdx.x >> 6;
    int lane = threadIdx.x & 63;
    int half = lane >> 5, lc = lane & 31;

    int swz = (blockIdx.x & 7) * XCHUNK + (blockIdx.x >> 3);
    // column-major upper-triangle decode: swz = j*(j+1)/2 + i, i <= j
    int j = (int)((sqrtf(8.0f * (float)swz + 1.0f) - 1.0f) * 0.5f);
    while ((j + 1) * (j + 2) / 2 <= swz) ++j;
    while (j * (j + 1) / 2 > swz) --j;
    int i = swz - j * (j + 1) / 2;
    bool doCol = (i < j);

    int rt0 = i * 4 + wid * 2;     // row-tiles (32-row units): rt0, rt0+1
    int ct0 = j * 4;               // first col-tile of strip j

    // A fragments: coalesced 1KB loads, held for the whole kernel
    const char* afrag = p + (size_t)rt0 * 8192 + half * 512 + lc * 16;
    short8 a0[8], a1[8];
#pragma unroll
    for (int kc = 0; kc < 8; ++kc) {
        a0[kc] = *reinterpret_cast<const short8*>(afrag + kc * 1024);
        a1[kc] = *reinterpret_cast<const short8*>(afrag + 8192 + kc * 1024);
    }

    float rs0[16], rs1[16];
#pragma unroll
    for (int q = 0; q < 16; ++q) { rs0[q] = 0.0f; rs1[q] = 0.0f; }
    float cs0 = 0.0f, cs1 = 0.0f, cs2 = 0.0f, cs3 = 0.0f;

    // each wave stages 4 of the 8 1KB segments of one 8KB col-tile
    auto stageHalf = [&](char* buf, int ct) {
#pragma unroll
        for (int sg = 0; sg < 4; ++sg) {
            int seg = wid * 4 + sg;
            const char* g = p + (size_t)ct * 8192 + seg * 1024 + lane * 16;
            __builtin_amdgcn_global_load_lds(
                (const __attribute__((address_space(1))) unsigned int*)g,
                (__attribute__((address_space(3))) unsigned int*)(buf + seg * 1024),
                16, 0, 0);
        }
    };

    auto compute = [&](const char* buf, float& cs) {
        const char* bb = buf + half * 512 + lc * 16;
        short8 b[8];
#pragma unroll
        for (int kc = 0; kc < 8; ++kc)
            b[kc] = *reinterpret_cast<const short8*>(bb + kc * 1024);
        f32x16 acc0 = {}, acc1 = {};
#pragma unroll
        for (int kc = 0; kc < 8; ++kc) {
            acc0 = __builtin_amdgcn_mfma_f32_32x32x16_bf16(a0[kc], b[kc], acc0, 0, 0, 0);
            acc1 = __builtin_amdgcn_mfma_f32_32x32x16_bf16(a1[kc], b[kc], acc1, 0, 0, 0);
        }
        float c01 = 0.0f;
#pragma unroll
        for (int q = 0; q < 16; ++q) {
            float e0 = __builtin_amdgcn_exp2f(acc0[q]);
            float e1 = __builtin_amdgcn_exp2f(acc1[q]);
            rs0[q] += e0;
            rs1[q] += e1;
            c01 += e0 + e1;
        }
        if (doCol) {                      // block-uniform branch
            c01 += __shfl_xor(c01, 32, 64);
            cs = c01;                     // full 64-row colsum, col = ct*32+lc
        }
    };

    stageHalf(bufA, ct0 + 0);
    __syncthreads();
    stageHalf(bufB, ct0 + 1);
    compute(bufA, cs0);
    __syncthreads();
    stageHalf(bufA, ct0 + 2);
    compute(bufB, cs1);
    __syncthreads();
    stageHalf(bufB, ct0 + 3);
    compute(bufA, cs2);
    __syncthreads();
    compute(bufB, cs3);

    // rowsum: reduce across the 32 column lanes
#pragma unroll
    for (int m = 1; m <= 16; m <<= 1) {
#pragma unroll
        for (int q = 0; q < 16; ++q) {
            rs0[q] += __shfl_xor(rs0[q], m, 64);
            rs1[q] += __shfl_xor(rs1[q], m, 64);
        }
    }
    if (lc == 0) {
        float* dst = partial + (size_t)j * N_SZ;
#pragma unroll
        for (int q = 0; q < 16; ++q) {
            int lrow = (q & 3) + 8 * (q >> 2) + 4 * half;
            dst[rt0 * 32 + lrow] = rs0[q];
            dst[(rt0 + 1) * 32 + lrow] = rs1[q];
        }
    }

    // colsum: combine the 2 waves via LDS, store to slot 64+i
    if (doCol) {
        if (half == 0) {
            colred[wid][0 * 32 + lc] = cs0;
            colred[wid][1 * 32 + lc] = cs1;
            colred[wid][2 * 32 + lc] = cs2;
            colred[wid][3 * 32 + lc] = cs3;
        }
        __syncthreads();
        int c = threadIdx.x;  // [0,128)
        partial[(size_t)(NRB + i) * N_SZ + j * 128 + c] =
            colred[0][c] + colred[1][c];
    }
}

// ---------------------------------------------------------------------------
// Kernel C: loss = sum(log(rowsum - selfexp))/2B + pos partials.
// 128 blocks x 64 threads. Row r reads its exactly-written 64 slots:
// rowpart slots j in [bi,64), colpart slots 64+i for i in [0,bi), bi=r>>7.
// ---------------------------------------------------------------------------
__global__ void lse_kernel(const float* __restrict__ partial,
                           const float* __restrict__ selfexp,
                           const float* __restrict__ posbuf,
                           float* __restrict__ out) {
    int r = blockIdx.x * 64 + threadIdx.x;
    int bi = r >> 7;   // uniform within a block (64 consecutive rows)
    float s = 0.0f;
    for (int jj = bi; jj < NRB; ++jj) s += partial[(size_t)jj * N_SZ + r];
    for (int ii = 0; ii < bi; ++ii) s += partial[(size_t)(NRB + ii) * N_SZ + r];
    s -= selfexp[r];
    float v = __logf(s) * (1.0f / (float)N_SZ);
    if (threadIdx.x < 8) v += posbuf[blockIdx.x * 8 + threadIdx.x];
#pragma unroll
    for (int m = 32; m >= 1; m >>= 1) v += __shfl_xor(v, m, 64);
    if (threadIdx.x == 0)
        atomicAdd(out, v);
}

// ---------------------------------------------------------------------------
extern "C" void kernel_launch(void* const* d_in, const int* in_sizes, int n_in,
                              void* d_out, int out_size, void* d_ws, size_t ws_size,
                              hipStream_t stream) {
    const float* z_i = (const float*)d_in[0];
    const float* z_j = (const float*)d_in[1];
    float* out = (float*)d_out;
    char* ws = (char*)d_ws;

    unsigned int* pn = (unsigned int*)ws;                            // 2 MiB
    float* partial = (float*)(ws + (size_t)N_SZ * D_SZ * 2);         // 4 MiB (128 x 8192)
    float* selfexp = partial + (size_t)2 * NRB * N_SZ;               // 32 KiB
    float* posbuf = selfexp + N_SZ;                                  // 4 KiB

    norm_pos_kernel<<<B_SZ / 4, 256, 0, stream>>>(z_i, z_j, pn, posbuf,
                                                  selfexp, out);

    simexp_kernel<<<NTRI, 128, 0, stream>>>((const char*)pn, partial);

    lse_kernel<<<N_SZ / 64, 64, 0, stream>>>(partial, selfexp, posbuf, out);
}